// Round 18
// baseline (962.629 us; speedup 1.0000x reference)
//
#include <hip/hip_runtime.h>

typedef unsigned short u16;
typedef __bf16 bf16x8 __attribute__((ext_vector_type(8)));
typedef float f32x4 __attribute__((ext_vector_type(4)));
typedef float f32x4v __attribute__((ext_vector_type(4)));
typedef u16 u16x4 __attribute__((ext_vector_type(4)));

__device__ __forceinline__ float bf2f(u16 u) {
    unsigned x = ((unsigned)u) << 16;
    return __builtin_bit_cast(float, x);
}
__device__ __forceinline__ u16 f2bf(float f) {
    unsigned x = __builtin_bit_cast(unsigned, f);
    unsigned r = (x + 0x7FFFu + ((x >> 16) & 1u)) >> 16;
    return (u16)r;
}

// ==== merged weight conversion + qkv-bias fuse: one grid-stride kernel ====
// Regions: [qkv interleave 3*L*DD][wo L*DD][w1 L*FD][w2 L*FD][head V*D]
//          [qkv bias interleave 6*2304 (f32 passthrough)]
__global__ __launch_bounds__(256) void cvt_all_kernel(
    const float* __restrict__ wq, const float* __restrict__ wk,
    const float* __restrict__ wv, const float* __restrict__ wo,
    const float* __restrict__ w1, const float* __restrict__ w2,
    const float* __restrict__ hw,
    const float* __restrict__ bq, const float* __restrict__ bk,
    const float* __restrict__ bv,
    u16* __restrict__ qkvw_b, u16* __restrict__ wo_b,
    u16* __restrict__ w1_b, u16* __restrict__ w2_b, u16* __restrict__ hw_b,
    float* __restrict__ qkvbias) {
    const long DD = 589824, FD = 2359296;
    const long N0 = 3 * 6 * DD;            // qkv region
    const long N1 = N0 + 6 * DD;           // + wo
    const long N2 = N1 + 6 * FD;           // + w1
    const long N3 = N2 + 6 * FD;           // + w2
    const long N4 = N3 + 24576000L;        // + head
    const long N5 = N4 + 6 * 2304;         // + qkv bias (f32 passthrough)
    for (long i = (long)blockIdx.x * 1024 + (long)threadIdx.x * 4; i < N5;
         i += (long)gridDim.x * 1024) {
        if (i >= N4) {                     // bias region: f32 -> f32 interleave
            long j = i - N4;
            long l = j / 2304, c = j - l * 2304;
            long which = c / 768, off = c - which * 768;
            const float* src = (which == 0 ? bq : (which == 1 ? bk : bv)) + l * 768 + off;
            *(f32x4v*)(qkvbias + j) = *(const f32x4v*)src;
            continue;
        }
        const float* src;
        u16* dst;
        if (i < N0) {
            long layer = i / (3 * DD);
            long rem = i - layer * 3 * DD;
            long which = rem / DD;
            long off = rem - which * DD;
            src = (which == 0 ? wq : (which == 1 ? wk : wv)) + layer * DD + off;
            dst = qkvw_b + i;              // fused layout == region layout
        } else if (i < N1) {
            src = wo + (i - N0); dst = wo_b + (i - N0);
        } else if (i < N2) {
            src = w1 + (i - N1); dst = w1_b + (i - N1);
        } else if (i < N3) {
            src = w2 + (i - N2); dst = w2_b + (i - N2);
        } else {
            src = hw + (i - N3); dst = hw_b + (i - N3);
        }
        f32x4v v = *(const f32x4v*)src;
        u16x4 o;
        o.x = f2bf(v.x); o.y = f2bf(v.y); o.z = f2bf(v.z); o.w = f2bf(v.w);
        *(u16x4*)dst = o;
    }
}

// ------- embed + layer-0 ln1 fused: h = tok[x]+pos; a = LN(h) -------
__global__ __launch_bounds__(256) void embed_ln_kernel(
    const int* __restrict__ x, const float* __restrict__ tok,
    const float* __restrict__ pos, float* __restrict__ h,
    const float* __restrict__ w, const float* __restrict__ b,
    u16* __restrict__ out) {
    __shared__ float red[4];
    int row = blockIdx.x;
    int t = row & 1023;
    long id = x[row];
    const float* te = tok + id * 768L;
    const float* pe = pos + (long)t * 768L;
    float* hr = h + (long)row * 768L;
    int tid = threadIdx.x, lane = tid & 63, wid = tid >> 6;
    float v0 = te[tid] + pe[tid];
    float v1 = te[tid + 256] + pe[tid + 256];
    float v2 = te[tid + 512] + pe[tid + 512];
    hr[tid] = v0; hr[tid + 256] = v1; hr[tid + 512] = v2;
    float s = v0 + v1 + v2;
    for (int o = 32; o; o >>= 1) s += __shfl_xor(s, o);
    if (lane == 0) red[wid] = s;
    __syncthreads();
    float mean = (red[0] + red[1] + red[2] + red[3]) * (1.f / 768.f);
    __syncthreads();
    float d0 = v0 - mean, d1 = v1 - mean, d2 = v2 - mean;
    float q = d0 * d0 + d1 * d1 + d2 * d2;
    for (int o = 32; o; o >>= 1) q += __shfl_xor(q, o);
    if (lane == 0) red[wid] = q;
    __syncthreads();
    float var = (red[0] + red[1] + red[2] + red[3]) * (1.f / 768.f);
    float rstd = rsqrtf(var + 1e-5f);
    u16* orow = out + (long)row * 768L;
    orow[tid]       = f2bf(d0 * rstd * w[tid]       + b[tid]);
    orow[tid + 256] = f2bf(d1 * rstd * w[tid + 256] + b[tid + 256]);
    orow[tid + 512] = f2bf(d2 * rstd * w[tid + 512] + b[tid + 512]);
}

// ------ redln (192 thr, f32x4): h += sum(partials)+bias; LN(h) -> a ------
__global__ __launch_bounds__(192) void redln_kernel(
    const float* __restrict__ part, long pstride, int S,
    const float* __restrict__ bias, float* __restrict__ h,
    const float* __restrict__ w, const float* __restrict__ b,
    u16* __restrict__ out) {
    __shared__ float red[3];
    int row = blockIdx.x;
    int tid = threadIdx.x, lane = tid & 63, wid = tid >> 6;
    long base = (long)row * 768 + tid * 4;
    f32x4v x = *(const f32x4v*)(h + base);
    f32x4v bb = *(const f32x4v*)(bias + tid * 4);
    x += bb;
    for (int s = 0; s < S; s++) x += *(const f32x4v*)(part + (long)s * pstride + base);
    *(f32x4v*)(h + base) = x;
    float s = x.x + x.y + x.z + x.w;
    for (int o = 32; o; o >>= 1) s += __shfl_xor(s, o);
    if (lane == 0) red[wid] = s;
    __syncthreads();
    float mean = (red[0] + red[1] + red[2]) * (1.f / 768.f);
    __syncthreads();
    f32x4v d = x - mean;
    float q = d.x * d.x + d.y * d.y + d.z * d.z + d.w * d.w;
    for (int o = 32; o; o >>= 1) q += __shfl_xor(q, o);
    if (lane == 0) red[wid] = q;
    __syncthreads();
    float var = (red[0] + red[1] + red[2]) * (1.f / 768.f);
    float rstd = rsqrtf(var + 1e-5f);
    f32x4v wv = *(const f32x4v*)(w + tid * 4);
    f32x4v bv = *(const f32x4v*)(b + tid * 4);
    u16x4 o;
    o.x = f2bf(d.x * rstd * wv.x + bv.x);
    o.y = f2bf(d.y * rstd * wv.y + bv.y);
    o.z = f2bf(d.z * rstd * wv.z + bv.z);
    o.w = f2bf(d.w * rstd * wv.w + bv.w);
    *(u16x4*)(out + base) = o;
}

// ---------------- flash attention (causal, DK=64, K/V double-buffered) ------
__global__ __launch_bounds__(256) void flash_kernel(
    const u16* __restrict__ qkv,   // [2048][2304]; q col 0, k col 768
    const u16* __restrict__ vT,    // [24][64][1024]
    u16* __restrict__ ctx) {       // [2048][768]
    int z = blockIdx.z;
    int zb = z / 12, zh = z - zb * 12;
    int qt = (int)gridDim.x - 1 - (int)blockIdx.x;  // big tiles first
    int q0 = qt * 64;
    int tid = threadIdx.x, lane = tid & 63, wid = tid >> 6;
    int rA = lane & 15, sA = lane >> 4;

    const u16* Qbase = qkv + (long)zb * 1024 * 2304 + zh * 64;
    const u16* Kbase = Qbase + 768;
    const u16* Vbase = vT + (long)z * 64 * 1024;

    __shared__ u16 Ks[2][64 * 64];
    __shared__ u16 Vs[2][64 * 64];
    __shared__ u16 Ps[4][16 * 64];

    bf16x8 aq[2];
    {
        const u16* qrow = Qbase + (long)(q0 + wid * 16 + rA) * 2304;
        aq[0] = *(const bf16x8*)(qrow + sA * 8);
        aq[1] = *(const bf16x8*)(qrow + 32 + sA * 8);
    }

    auto stage = [&](int buf, int kv0) {
#pragma unroll
        for (int c0 = 0; c0 < 512; c0 += 256) {
            int c = c0 + tid;
            int row = c >> 3, half = (c >> 2) & 1, sl = c & 3;
            int ks = sl ^ ((row >> 1) & 3);
            __builtin_amdgcn_global_load_lds(
                (const __attribute__((address_space(1))) unsigned*)(Kbase + (long)(kv0 + row) * 2304 + half * 32 + ks * 8),
                (__attribute__((address_space(3))) unsigned*)(Ks[buf] + c * 8), 16, 0, 0);
        }
#pragma unroll
        for (int c0 = 0; c0 < 512; c0 += 256) {
            int c = c0 + tid;
            int row = c >> 3, half = (c >> 2) & 1, sl = c & 3;
            int ks = sl ^ ((row >> 1) & 3);
            __builtin_amdgcn_global_load_lds(
                (const __attribute__((address_space(1))) unsigned*)(Vbase + (long)row * 1024 + kv0 + half * 32 + ks * 8),
                (__attribute__((address_space(3))) unsigned*)(Vs[buf] + c * 8), 16, 0, 0);
        }
    };

    float m[4], l[4];
    f32x4 acc_o[4];
#pragma unroll
    for (int j = 0; j < 4; j++) { m[j] = -1e30f; l[j] = 0.f; }
#pragma unroll
    for (int nf = 0; nf < 4; nf++) acc_o[nf] = 0.f;

    int grow0 = q0 + wid * 16 + sA * 4;
    int nkv = qt + 1;

    stage(0, 0);
    __syncthreads();
    for (int t = 0; t < nkv; ++t) {
        int cur = t & 1;
        int kv0 = t * 64;
        if (t + 1 < nkv) stage(cur ^ 1, (t + 1) * 64);

        f32x4 s[4];
#pragma unroll
        for (int nf = 0; nf < 4; nf++) s[nf] = 0.f;
        __builtin_amdgcn_s_setprio(1);
#pragma unroll
        for (int h = 0; h < 2; h++)
#pragma unroll
            for (int nf = 0; nf < 4; nf++) {
                int row = nf * 16 + rA;
                bf16x8 bk_ = *(const bf16x8*)(Ks[cur] + row * 64 + h * 32 + ((sA ^ ((row >> 1) & 3))) * 8);
                s[nf] = __builtin_amdgcn_mfma_f32_16x16x32_bf16(aq[h], bk_, s[nf], 0, 0, 0);
            }
        __builtin_amdgcn_s_setprio(0);
#pragma unroll
        for (int nf = 0; nf < 4; nf++) {
            int col = kv0 + nf * 16 + rA;
#pragma unroll
            for (int j = 0; j < 4; j++)
                s[nf][j] = (col <= grow0 + j) ? s[nf][j] * 0.125f : -1e30f;
        }
        float pm[4];
#pragma unroll
        for (int j = 0; j < 4; j++) {
            float v = fmaxf(fmaxf(s[0][j], s[1][j]), fmaxf(s[2][j], s[3][j]));
#pragma unroll
            for (int o = 1; o < 16; o <<= 1) v = fmaxf(v, __shfl_xor(v, o));
            pm[j] = v;
        }
        float esc[4];
#pragma unroll
        for (int j = 0; j < 4; j++) {
            float mn = fmaxf(m[j], pm[j]);
            esc[j] = __expf(m[j] - mn);
            m[j] = mn;
        }
        float ts[4] = {0.f, 0.f, 0.f, 0.f};
#pragma unroll
        for (int nf = 0; nf < 4; nf++) {
            int c = nf * 16 + rA;
            int half = c >> 5, ch = (c >> 3) & 3, e = c & 7;
#pragma unroll
            for (int j = 0; j < 4; j++) {
                float p = __expf(s[nf][j] - m[j]);
                ts[j] += p;
                int r = sA * 4 + j;
                Ps[wid][r * 64 + half * 32 + (ch ^ ((r >> 1) & 3)) * 8 + e] = f2bf(p);
            }
        }
#pragma unroll
        for (int j = 0; j < 4; j++) {
            float v = ts[j];
#pragma unroll
            for (int o = 1; o < 16; o <<= 1) v += __shfl_xor(v, o);
            l[j] = l[j] * esc[j] + v;
        }
#pragma unroll
        for (int nf = 0; nf < 4; nf++)
#pragma unroll
            for (int j = 0; j < 4; j++) acc_o[nf][j] *= esc[j];

        __builtin_amdgcn_s_setprio(1);
#pragma unroll
        for (int h = 0; h < 2; h++) {
            bf16x8 ap = *(const bf16x8*)(Ps[wid] + rA * 64 + h * 32 + ((sA ^ ((rA >> 1) & 3))) * 8);
#pragma unroll
            for (int nf = 0; nf < 4; nf++) {
                int row = nf * 16 + rA;
                bf16x8 bv_ = *(const bf16x8*)(Vs[cur] + row * 64 + h * 32 + ((sA ^ ((row >> 1) & 3))) * 8);
                acc_o[nf] = __builtin_amdgcn_mfma_f32_16x16x32_bf16(ap, bv_, acc_o[nf], 0, 0, 0);
            }
        }
        __builtin_amdgcn_s_setprio(0);
        __syncthreads();  // drains stage(t+1); protects buffers for next iter
    }

    float inv[4];
#pragma unroll
    for (int j = 0; j < 4; j++) inv[j] = 1.f / l[j];
    u16* crow = ctx + ((long)zb * 1024 + q0 + wid * 16) * 768 + zh * 64;
#pragma unroll
    for (int nf = 0; nf < 4; nf++)
#pragma unroll
        for (int j = 0; j < 4; j++)
            crow[(long)(sA * 4 + j) * 768 + nf * 16 + rA] = f2bf(acc_o[nf][j] * inv[j]);
}

// ==== MFMA GEMM v8: 2-phase dbuf + swizzle, template BK, split-K ====
// EPI: 2 relu(+bias) bf16; 5 f32 (+slice*partStride); 6 qkv-split.
template <int BM, int BN, int BK, int EPI, int SK>
__global__ __launch_bounds__(256) void gemm8_kernel(
    const u16* __restrict__ A, int lda,
    const u16* __restrict__ Bm, int ldb,
    void* __restrict__ Cv, int ldc,
    const float* __restrict__ bias, int Kslice, int gm,
    u16* __restrict__ aux, long partStride) {
    constexpr int CPR = BK / 8;      // 16B chunks per row
    constexpr int KH = BK / 32;      // MFMA k-steps per tile
    int flat = blockIdx.x;
    int tid = threadIdx.x;
    int nwg = gridDim.x;
    int qq = nwg >> 3, rr = nwg & 7;
    int xcd = flat & 7, wi = flat >> 3;
    int swz = (xcd < rr) ? (xcd * (qq + 1) + wi) : (rr * (qq + 1) + (xcd - rr) * qq + wi);
    int slice = 0, wblk = swz;
    if (SK > 1) { int nbs = nwg / SK; slice = swz / nbs; wblk = swz - slice * nbs; }
    int ntile = wblk / gm, mt = wblk - ntile * gm;
    int bm0 = mt * BM, bn0 = ntile * BN;
    long koff = (long)slice * Kslice;
    const u16* Ab = A + (long)bm0 * lda + koff;
    const u16* Bb = Bm + (long)bn0 * ldb + koff;

    __shared__ u16 As[2][BM * BK];
    __shared__ u16 Bs[2][BN * BK];

    int lane = tid & 63, wid = tid >> 6;
    constexpr int WM = BM / 2, WN = BN / 2, MR = WM / 16, NR = WN / 16;
    int wm0 = (wid >> 1) * WM, wn0 = (wid & 1) * WN;

    f32x4 acc[MR][NR];
#pragma unroll
    for (int mi = 0; mi < MR; mi++)
#pragma unroll
        for (int ni = 0; ni < NR; ni++) acc[mi][ni] = 0.f;

    int nt = Kslice / BK;

    auto key = [](int row) { return (BK == 32) ? ((row >> 1) & 3) : (row & 7); };

    auto stage = [&](int buf, int k0) {
        constexpr int CA = BM * CPR;
#pragma unroll
        for (int c0 = 0; c0 < CA; c0 += 256) {
            int c = c0 + tid;
            int row = c / CPR, sl = c & (CPR - 1);
            int ks = sl ^ key(row);
            __builtin_amdgcn_global_load_lds(
                (const __attribute__((address_space(1))) unsigned*)(Ab + (long)row * lda + k0 + ks * 8),
                (__attribute__((address_space(3))) unsigned*)(As[buf] + c * 8), 16, 0, 0);
        }
        constexpr int CB = BN * CPR;
#pragma unroll
        for (int c0 = 0; c0 < CB; c0 += 256) {
            int c = c0 + tid;
            int row = c / CPR, sl = c & (CPR - 1);
            int ks = sl ^ key(row);
            __builtin_amdgcn_global_load_lds(
                (const __attribute__((address_space(1))) unsigned*)(Bb + (long)row * ldb + k0 + ks * 8),
                (__attribute__((address_space(3))) unsigned*)(Bs[buf] + c * 8), 16, 0, 0);
        }
    };

    stage(0, 0);
    __syncthreads();
    int cur = 0;
    int rA = lane & 15, sA = lane >> 4;
    for (int t = 0; t < nt; ++t) {
        if (t + 1 < nt) stage(cur ^ 1, (t + 1) * BK);
        bf16x8 af[MR][KH], bfr[NR][KH];
#pragma unroll
        for (int mi = 0; mi < MR; mi++) {
            int row = wm0 + mi * 16 + rA;
#pragma unroll
            for (int h = 0; h < KH; h++)
                af[mi][h] = *(const bf16x8*)(As[cur] + row * BK + (((h << 2) + sA) ^ key(row)) * 8);
        }
#pragma unroll
        for (int ni = 0; ni < NR; ni++) {
            int row = wn0 + ni * 16 + rA;
#pragma unroll
            for (int h = 0; h < KH; h++)
                bfr[ni][h] = *(const bf16x8*)(Bs[cur] + row * BK + (((h << 2) + sA) ^ key(row)) * 8);
        }
#pragma unroll
        for (int h = 0; h < KH; h++)
#pragma unroll
            for (int mi = 0; mi < MR; mi++)
#pragma unroll
                for (int ni = 0; ni < NR; ni++)
                    acc[mi][ni] = __builtin_amdgcn_mfma_f32_16x16x32_bf16(
                        af[mi][h], bfr[ni][h], acc[mi][ni], 0, 0, 0);
        __syncthreads();
        cur ^= 1;
    }

#pragma unroll
    for (int mi = 0; mi < MR; mi++)
#pragma unroll
        for (int ni = 0; ni < NR; ni++) {
            int gmb = bm0 + wm0 + mi * 16 + ((lane >> 4) << 2);
            int gn = bn0 + wn0 + ni * 16 + (lane & 15);
            if (EPI == 6) {
                if (gn < 1536) {
#pragma unroll
                    for (int j = 0; j < 4; j++)
                        ((u16*)Cv)[(long)(gmb + j) * ldc + gn] =
                            f2bf(acc[mi][ni][j] + bias[gn]);
                } else {
                    u16x4 o;
#pragma unroll
                    for (int j = 0; j < 4; j++) o[j] = f2bf(acc[mi][ni][j] + bias[gn]);
                    int hh = (gn - 1536) >> 6, dk = gn & 63;
                    long off = ((long)((gmb >> 10) * 12 + hh) * 64 + dk) * 1024 + (gmb & 1023);
                    *(u16x4*)(aux + off) = o;
                }
            } else {
#pragma unroll
                for (int j = 0; j < 4; j++) {
                    float v = acc[mi][ni][j];
                    long idx = (long)(gmb + j) * ldc + gn;
                    if (EPI == 2) ((u16*)Cv)[idx] = f2bf(fmaxf(v + bias[gn], 0.f));
                    else ((float*)Cv)[(long)slice * partStride + idx] = v;  // EPI 5
                }
            }
        }
}

// ---------------- host side ----------------
extern "C" void kernel_launch(void* const* d_in, const int* in_sizes, int n_in,
                              void* d_out, int out_size, void* d_ws, size_t ws_size,
                              hipStream_t stream) {
    const int L = 6, D = 768, F = 3072, T = 1024, V = 32000;
    const int M = 2048;  // B*T
    const int* x = (const int*)d_in[0];
    const float* tok = (const float*)d_in[1];
    const float* pos = (const float*)d_in[2];
    const float* ln1w = (const float*)d_in[3];
    const float* ln1b = (const float*)d_in[4];
    const float* wq = (const float*)d_in[5];
    const float* bq = (const float*)d_in[6];
    const float* wk = (const float*)d_in[7];
    const float* bk = (const float*)d_in[8];
    const float* wv = (const float*)d_in[9];
    const float* bv = (const float*)d_in[10];
    const float* wo = (const float*)d_in[11];
    const float* bo = (const float*)d_in[12];
    const float* ln2w = (const float*)d_in[13];
    const float* ln2b = (const float*)d_in[14];
    const float* w1 = (const float*)d_in[15];
    const float* b1 = (const float*)d_in[16];
    const float* w2 = (const float*)d_in[17];
    const float* b2 = (const float*)d_in[18];
    const float* lnfw = (const float*)d_in[19];
    const float* lnfb = (const float*)d_in[20];
    const float* headw = (const float*)d_in[21];

    char* p = (char*)d_ws;
    auto alloc = [&](size_t bytes) {
        char* r = p;
        p += (bytes + 255) & ~(size_t)255;
        return r;
    };
    const long DD = (long)D * D, FD = (long)F * D;
    const long PS = (long)M * D;                 // partial stride (f32 elems)
    u16* qkvw_b = (u16*)alloc(L * 3 * DD * 2);   // [L][2304][768] fused
    u16* wo_b = (u16*)alloc(L * DD * 2);
    u16* w1_b = (u16*)alloc(L * FD * 2);
    u16* w2_b = (u16*)alloc(L * FD * 2);
    u16* hw_b = (u16*)alloc((long)V * D * 2);
    float* qkvbias = (float*)alloc(L * 2304 * 4);
    float* h = (float*)alloc((long)M * D * 4);
    u16* a = (u16*)alloc((long)M * D * 2);
    u16* qkvb = (u16*)alloc((long)M * 2304 * 2);
    u16* vT = (u16*)alloc(24L * 64 * T * 2);     // [B*H][64][T]
    u16* ctxb = (u16*)alloc((long)M * D * 2);
    u16* f1 = (u16*)alloc((long)M * F * 2);
    float* part = (float*)alloc(4L * PS * 4);    // split-K partials [4][2048][768]

    // single merged conversion pass (weights + qkv bias interleave)
    cvt_all_kernel<<<dim3(4096), 256, 0, stream>>>(
        wq, wk, wv, wo, w1, w2, headw, bq, bk, bv,
        qkvw_b, wo_b, w1_b, w2_b, hw_b, qkvbias);
    // fused embed + layer-0 ln1
    embed_ln_kernel<<<dim3(M), 256, 0, stream>>>(x, tok, pos, h, ln1w, ln1b, a);

    for (int i = 0; i < L; i++) {
        int nx = i + 1;
        bool hn = nx < L;
        // qkv = a @ qkvw^T + bias ; v -> vT. 64x128 BK=64, 12 steps.
        gemm8_kernel<64, 128, 64, 6, 1><<<dim3(576), 256, 0, stream>>>(
            a, D, qkvw_b + i * 3 * DD, D, qkvb, 2304, qkvbias + i * 2304,
            D, 32, vT, 0);
        flash_kernel<<<dim3(16, 1, 24), 256, 0, stream>>>(qkvb, vT, ctxb);
        // wo split-K=2 (Kslice=384, 6 steps) -> partials
        gemm8_kernel<64, 128, 64, 5, 2><<<dim3(384), 256, 0, stream>>>(
            ctxb, D, wo_b + i * DD, D, part, D, nullptr, 384, 32, nullptr, PS);
        // h += p0+p1 + bo ; a = LN(h, ln2)
        redln_kernel<<<dim3(M), 192, 0, stream>>>(
            part, PS, 2, bo + i * D, h, ln2w + i * D, ln2b + i * D, a);
        // f1 = relu(a @ w1^T + b1). 64x128 BK=64, 12 steps.
        gemm8_kernel<64, 128, 64, 2, 1><<<dim3(768), 256, 0, stream>>>(
            a, D, w1_b + i * FD, D, f1, F, b1 + i * F, D, 32, nullptr, 0);
        // ffn2 split-K=4 (Kslice=768, 12 steps) -> partials
        gemm8_kernel<64, 128, 64, 5, 4><<<dim3(768), 256, 0, stream>>>(
            f1, F, w2_b + i * FD, F, part, D, nullptr, 768, 32, nullptr, PS);
        // h += p0..p3 + b2 ; a = LN(h, next ln1 or lnf)
        redln_kernel<<<dim3(M), 192, 0, stream>>>(
            part, PS, 4, b2 + i * D, h,
            hn ? ln1w + nx * D : lnfw, hn ? ln1b + nx * D : lnfb, a);
    }
    // logits = a @ head_w^T -> f32 d_out (128x128 BK=32, best-measured)
    gemm8_kernel<128, 128, 32, 5, 1><<<dim3(4000), 256, 0, stream>>>(
        a, D, hw_b, D, d_out, V, nullptr, D, 16, nullptr, 0);
}